// Round 4
// baseline (48.024 us; speedup 1.0000x reference)
//
#include <hip/hip_runtime.h>

typedef float f32x4 __attribute__((ext_vector_type(4)));
typedef short bf16x8 __attribute__((ext_vector_type(8)));
typedef __bf16 bf16x2_t __attribute__((ext_vector_type(2)));
typedef unsigned int u32;
typedef unsigned long long u64;

__device__ __forceinline__ u32 pk2(float a, float b){
  bf16x2_t h; h[0] = (__bf16)a; h[1] = (__bf16)b;
  return __builtin_bit_cast(u32, h);
}
__device__ __forceinline__ unsigned short f2bf(float f){
  __bf16 h = (__bf16)f;
  return __builtin_bit_cast(unsigned short, h);
}
__device__ __forceinline__ float bf2f(unsigned short h){
  u32 u = ((u32)h) << 16;
  return __builtin_bit_cast(float, u);
}

// ws layout in ushort (bf16) units
#define WS_WQT   0u        // [64][512]  WqT[n][k]
#define WS_WKT   32768u
#define WS_WVT   65536u
#define WS_WOFT  98304u    // [512][64]  Wo_foldT[n][k]
#define WS_QP    131072u   // [8192][64]  qp * 0.125*log2(e) folded
#define WS_KP    655360u   // [8192][64]
#define WS_VPT   1179648u  // [4][64][2048]  vp transposed per batch

#define QSCALE 0.18033688011112042f   // 0.125 * log2(e)

// ---------------- K1: fold Wo, transpose+cast weights to bf16 ----------------
__global__ __launch_bounds__(256) void k_prep(const float* __restrict__ Wq,
    const float* __restrict__ Wk, const float* __restrict__ Wv,
    const float* __restrict__ Wo, unsigned short* __restrict__ wsu){
  int id = blockIdx.x * 256 + threadIdx.x;   // grid 512*256 = 131072 exactly
  int which = id >> 15;
  int r = id & 32767;
  if (which < 3){
    const float* W = which==0 ? Wq : (which==1 ? Wk : Wv);
    int n = r >> 9, k = r & 511;             // WT[n][k] = W[k][n]
    wsu[which*32768u + r] = f2bf(W[k*64 + n]);
  } else {
    int n = r >> 6, k = r & 63;              // Wo_foldT[n][k] = sum_h Wo[h*64+k][n]
    float s = 0.f;
    #pragma unroll
    for (int h = 0; h < 8; ++h) s += Wo[(h*64 + k)*512 + n];
    wsu[WS_WOFT + r] = f2bf(s);
  }
}

// ---------------- K2: projection GEMM (8192x512)@(512x64) x3 ----------------
// 32 rows/block, 128 threads, grid (256,3) = 768 blocks; dbuf LDS, reg prefetch
__global__ __launch_bounds__(128) void k_proj(const float* __restrict__ q,
    const float* __restrict__ kmat, const float* __restrict__ v,
    const float* __restrict__ bq, const float* __restrict__ bk,
    const float* __restrict__ bv, unsigned short* __restrict__ wsu){
  __shared__ unsigned short Xs[2][2048];     // 2 x (32 rows x 64 k) bf16, XOR-swizzled
  const int which = blockIdx.y;
  const float* X    = which==0 ? q  : (which==1 ? kmat : v);
  const float* bias = which==0 ? bq : (which==1 ? bk   : bv);
  const unsigned short* WT = wsu + which*32768u;
  const int rowbase = blockIdx.x * 32;
  const int t = threadIdx.x;
  const int w = t >> 6, l = t & 63, g = l >> 4, ln = l & 15;

  f32x4 acc[2][2];                           // [rt][ntl]
  #pragma unroll
  for (int rt = 0; rt < 2; ++rt)
    #pragma unroll
    for (int ntl = 0; ntl < 2; ++ntl) acc[rt][ntl] = (f32x4){0.f,0.f,0.f,0.f};
  float bcol[2];
  #pragma unroll
  for (int ntl = 0; ntl < 2; ++ntl) bcol[ntl] = bias[(w*2+ntl)*16 + ln];

  f32x4 xr[4];
  bf16x8 bc[2][2], bn[2][2];

  // prologue: chunk 0 X + B
  #pragma unroll
  for (int j = 0; j < 4; ++j){
    int c = t + j*128; int row = c >> 4, kc = c & 15;
    xr[j] = __builtin_nontemporal_load(reinterpret_cast<const f32x4*>(X + (rowbase+row)*512 + kc*4));
  }
  #pragma unroll
  for (int ntl = 0; ntl < 2; ++ntl)
    #pragma unroll
    for (int kt = 0; kt < 2; ++kt)
      bc[ntl][kt] = *reinterpret_cast<const bf16x8*>(WT + ((w*2+ntl)*16+ln)*512 + kt*32 + g*8);

  #pragma unroll
  for (int i = 0; i < 8; ++i){
    char* Xc = reinterpret_cast<char*>(Xs[i & 1]);
    // stage current chunk regs -> LDS (convert)
    #pragma unroll
    for (int j = 0; j < 4; ++j){
      int c = t + j*128; int row = c >> 4, kc = c & 15;
      u64 pk = (u64)pk2(xr[j][0], xr[j][1]) | ((u64)pk2(xr[j][2], xr[j][3]) << 32);
      *reinterpret_cast<u64*>(Xc + row*128 + ((kc*8) ^ ((row&7)<<4))) = pk;
    }
    // issue next chunk loads
    if (i < 7){
      #pragma unroll
      for (int j = 0; j < 4; ++j){
        int c = t + j*128; int row = c >> 4, kc = c & 15;
        xr[j] = __builtin_nontemporal_load(reinterpret_cast<const f32x4*>(X + (rowbase+row)*512 + (i+1)*64 + kc*4));
      }
    }
    __syncthreads();
    if (i < 7){
      #pragma unroll
      for (int ntl = 0; ntl < 2; ++ntl)
        #pragma unroll
        for (int kt = 0; kt < 2; ++kt)
          bn[ntl][kt] = *reinterpret_cast<const bf16x8*>(WT + ((w*2+ntl)*16+ln)*512 + (i+1)*64 + kt*32 + g*8);
    }
    bf16x8 a[2][2];
    #pragma unroll
    for (int rt = 0; rt < 2; ++rt){
      int arow = rt*16 + ln;
      #pragma unroll
      for (int kt = 0; kt < 2; ++kt)
        a[rt][kt] = *reinterpret_cast<const bf16x8*>(Xc + arow*128 + ((kt*64 + g*16) ^ ((arow&7)<<4)));
    }
    #pragma unroll
    for (int ntl = 0; ntl < 2; ++ntl)
      #pragma unroll
      for (int kt = 0; kt < 2; ++kt)
        #pragma unroll
        for (int rt = 0; rt < 2; ++rt)
          acc[rt][ntl] = __builtin_amdgcn_mfma_f32_16x16x32_bf16(a[rt][kt], bc[ntl][kt], acc[rt][ntl], 0, 0, 0);
    if (i < 7){
      #pragma unroll
      for (int ntl = 0; ntl < 2; ++ntl)
        #pragma unroll
        for (int kt = 0; kt < 2; ++kt)
          bc[ntl][kt] = bn[ntl][kt];
    }
  }

  if (which < 2){
    const float sc = (which==0) ? QSCALE : 1.0f;
    unsigned short* outp = wsu + (which==0 ? WS_QP : WS_KP);
    #pragma unroll
    for (int rt = 0; rt < 2; ++rt)
      #pragma unroll
      for (int ntl = 0; ntl < 2; ++ntl)
        #pragma unroll
        for (int r = 0; r < 4; ++r)
          outp[(rowbase + rt*16 + g*4 + r)*64 + (w*2+ntl)*16 + ln] = f2bf((acc[rt][ntl][r] + bcol[ntl]) * sc);
  } else {
    // V: round-trip through LDS, store transposed vpT[b][d][kv]
    __syncthreads();
    #pragma unroll
    for (int rt = 0; rt < 2; ++rt)
      #pragma unroll
      for (int ntl = 0; ntl < 2; ++ntl)
        #pragma unroll
        for (int r = 0; r < 4; ++r)
          Xs[0][(rt*16 + g*4 + r)*64 + (w*2+ntl)*16 + ln] = f2bf(acc[rt][ntl][r] + bcol[ntl]);
    __syncthreads();
    unsigned short* vpT = wsu + WS_VPT;
    const int b = rowbase >> 11;
    const int kvb = rowbase & 2047;
    const int d = t >> 1, seg = t & 1;       // 64 d x 2 segs of 16 kv
    bf16x8 v0, v1;
    #pragma unroll
    for (int i = 0; i < 8; ++i){
      v0[i] = (short)Xs[0][(seg*16 + i)*64 + d];
      v1[i] = (short)Xs[0][(seg*16 + 8 + i)*64 + d];
    }
    unsigned short* dst = vpT + ((unsigned)(b*64 + d))*2048u + kvb + seg*16;
    *reinterpret_cast<bf16x8*>(dst)     = v0;
    *reinterpret_cast<bf16x8*>(dst + 8) = v1;
  }
}

// ---------------- K3: split-KV flash attention + fused output projection ----
// KVBLK=64, 4 iters, ka prefetch; exp2-based softmax (scale folded into qp).
// LDS overlay: per-wave P buffer (stride 72 us) reused as partial-O (stride 68).
#define PSTR 72

__global__ __launch_bounds__(512, 2) void k_attn(const unsigned short* __restrict__ wsu,
    const float* __restrict__ bo, float* __restrict__ out){
  __shared__ __attribute__((aligned(16))) unsigned char smem[42496];
  // [0, 36864)      : per-wave region, w*4608: P rows 32 x stride 144B, then reused as po rows 32 x stride 136B
  // [36864, 37888)  : pls float[8][32]
  // [37888, 42496)  : ob ushort rows 32 x stride 144B

  const unsigned short* qp   = wsu + WS_QP;
  const unsigned short* kp   = wsu + WS_KP;
  const unsigned short* vpT  = wsu + WS_VPT;
  const unsigned short* WofT = wsu + WS_WOFT;

  const int t = threadIdx.x;
  const int w = t >> 6, l = t & 63, g = l >> 4, ln = l & 15;
  const int batch = blockIdx.y;
  const int qbase = batch*2048 + blockIdx.x*32;

  unsigned short* Pw  = (unsigned short*)(smem + w*4608);
  float*          pls = (float*)(smem + 36864);
  unsigned short* ob  = (unsigned short*)(smem + 37888);

  // Q fragments (B-operand: rows q = rt*16+ln, k = kt*32 + g*8 .. +7)
  bf16x8 qa[2][2];
  #pragma unroll
  for (int rt = 0; rt < 2; ++rt)
    #pragma unroll
    for (int kt = 0; kt < 2; ++kt)
      qa[rt][kt] = *reinterpret_cast<const bf16x8*>(qp + (qbase + rt*16 + ln)*64 + kt*32 + g*8);

  f32x4 o[4][2];                                 // O^T tiles [dt][rt]
  #pragma unroll
  for (int dt = 0; dt < 4; ++dt)
    #pragma unroll
    for (int rt = 0; rt < 2; ++rt) o[dt][rt] = (f32x4){0.f,0.f,0.f,0.f};
  float ls[2] = {0.f, 0.f};

  const unsigned short* kpb = kp  + batch*2048*64;
  const unsigned short* vpb = vpT + batch*64*2048;
  const int kv0 = w * 256;                       // this wave's KV slice

  bf16x8 ka[4][2];
  #pragma unroll
  for (int ct = 0; ct < 4; ++ct)
    #pragma unroll
    for (int kt = 0; kt < 2; ++kt)
      ka[ct][kt] = *reinterpret_cast<const bf16x8*>(kpb + (kv0 + ct*16 + ln)*64 + kt*32 + g*8);

  #pragma unroll
  for (int it = 0; it < 4; ++it){
    const int kvb = kv0 + it*64;
    // S^T(64kv x 32q) = mfma(A=K rows, B=Q rows); kv=ct*16+g*4+r, q=rt*16+ln
    f32x4 st[4][2];
    #pragma unroll
    for (int ct = 0; ct < 4; ++ct)
      #pragma unroll
      for (int rt = 0; rt < 2; ++rt){
        st[ct][rt] = (f32x4){0.f,0.f,0.f,0.f};
        #pragma unroll
        for (int kt = 0; kt < 2; ++kt)
          st[ct][rt] = __builtin_amdgcn_mfma_f32_16x16x32_bf16(ka[ct][kt], qa[rt][kt], st[ct][rt], 0,0,0);
      }
    // prefetch next iter's K fragments (hidden under softmax+PV)
    bf16x8 kan[4][2];
    if (it < 3){
      #pragma unroll
      for (int ct = 0; ct < 4; ++ct)
        #pragma unroll
        for (int kt = 0; kt < 2; ++kt)
          kan[ct][kt] = *reinterpret_cast<const bf16x8*>(kpb + (kvb + 64 + ct*16 + ln)*64 + kt*32 + g*8);
    }
    // V fragments for this iter (latency hidden under softmax)
    bf16x8 vb[4][2];
    #pragma unroll
    for (int dt = 0; dt < 4; ++dt)
      #pragma unroll
      for (int kvt = 0; kvt < 2; ++kvt)
        vb[dt][kvt] = *reinterpret_cast<const bf16x8*>(vpb + (dt*16 + ln)*2048 + kvb + kvt*32 + g*8);

    // softmax: p = exp2(st) (qp pre-scaled); lane-local sum + 2 shuffles
    #pragma unroll
    for (int rt = 0; rt < 2; ++rt){
      float p[4][4];
      float rs = 0.f;
      #pragma unroll
      for (int ct = 0; ct < 4; ++ct)
        #pragma unroll
        for (int r = 0; r < 4; ++r){
          p[ct][r] = exp2f(st[ct][rt][r]);
          rs += p[ct][r];
        }
      rs += __shfl_xor(rs, 16, 64);
      rs += __shfl_xor(rs, 32, 64);
      ls[rt] += rs;
      unsigned short* pr = Pw + (rt*16 + ln)*PSTR;
      #pragma unroll
      for (int ct = 0; ct < 4; ++ct){
        *reinterpret_cast<u32*>(pr + ct*16 + g*4)     = pk2(p[ct][0], p[ct][1]);
        *reinterpret_cast<u32*>(pr + ct*16 + g*4 + 2) = pk2(p[ct][2], p[ct][3]);
      }
    }
    // PV: O^T += mfma(A=V^T, B=P^T-as-B)  (wave-private LDS)
    bf16x8 pb[2][2];
    #pragma unroll
    for (int rt = 0; rt < 2; ++rt)
      #pragma unroll
      for (int kvt = 0; kvt < 2; ++kvt)
        pb[rt][kvt] = *reinterpret_cast<const bf16x8*>(Pw + (rt*16 + ln)*PSTR + kvt*32 + g*8);
    #pragma unroll
    for (int dt = 0; dt < 4; ++dt)
      #pragma unroll
      for (int rt = 0; rt < 2; ++rt)
        #pragma unroll
        for (int kvt = 0; kvt < 2; ++kvt)
          o[dt][rt] = __builtin_amdgcn_mfma_f32_16x16x32_bf16(vb[dt][kvt], pb[rt][kvt], o[dt][rt], 0,0,0);
    if (it < 3){
      #pragma unroll
      for (int ct = 0; ct < 4; ++ct)
        #pragma unroll
        for (int kt = 0; kt < 2; ++kt)
          ka[ct][kt] = kan[ct][kt];
    }
  }

  // write per-wave partials (overlay po on P region; data-dep ordering is safe)
  if (l < 16){ pls[w*32 + ln] = ls[0]; pls[w*32 + 16 + ln] = ls[1]; }
  unsigned short* pow_ = (unsigned short*)(smem + w*4608);
  #pragma unroll
  for (int dt = 0; dt < 4; ++dt)
    #pragma unroll
    for (int rt = 0; rt < 2; ++rt){
      u32* dst = reinterpret_cast<u32*>(pow_ + (rt*16 + ln)*68 + dt*16 + g*4);
      dst[0] = pk2(o[dt][rt][0], o[dt][rt][1]);
      dst[1] = pk2(o[dt][rt][2], o[dt][rt][3]);
    }
  __syncthreads();

  // merge 8 wave-partials -> normalized O (bf16, stride 72)
  #pragma unroll
  for (int i = 0; i < 4; ++i){
    int idx = t + i*512;
    int row = idx >> 6, d = idx & 63;
    float den = 0.f, num = 0.f;
    #pragma unroll
    for (int w2 = 0; w2 < 8; ++w2){
      den += pls[w2*32 + row];
      num += bf2f(*((const unsigned short*)(smem + w2*4608) + row*68 + d));
    }
    ob[row*PSTR + d] = f2bf(num / den);
  }
  __syncthreads();

  // output projection: out(32x512) = O(32x64) @ Wo_fold(64x512), + bo
  const int colbase = w*64;
  bf16x8 ao[2][2];
  #pragma unroll
  for (int rt = 0; rt < 2; ++rt)
    #pragma unroll
    for (int kt = 0; kt < 2; ++kt)
      ao[rt][kt] = *reinterpret_cast<const bf16x8*>(ob + (rt*16 + ln)*PSTR + kt*32 + g*8);
  f32x4 oc[2][4];
  #pragma unroll
  for (int rt = 0; rt < 2; ++rt)
    #pragma unroll
    for (int nt = 0; nt < 4; ++nt) oc[rt][nt] = (f32x4){0.f,0.f,0.f,0.f};
  #pragma unroll
  for (int nt = 0; nt < 4; ++nt){
    #pragma unroll
    for (int kt = 0; kt < 2; ++kt){
      bf16x8 b = *reinterpret_cast<const bf16x8*>(WofT + (colbase + nt*16 + ln)*64 + kt*32 + g*8);
      #pragma unroll
      for (int rt = 0; rt < 2; ++rt)
        oc[rt][nt] = __builtin_amdgcn_mfma_f32_16x16x32_bf16(ao[rt][kt], b, oc[rt][nt], 0,0,0);
    }
  }
  #pragma unroll
  for (int nt = 0; nt < 4; ++nt){
    float bc = bo[colbase + nt*16 + ln];
    #pragma unroll
    for (int rt = 0; rt < 2; ++rt){
      #pragma unroll
      for (int r = 0; r < 4; ++r){
        int row = qbase + rt*16 + g*4 + r;
        __builtin_nontemporal_store(oc[rt][nt][r] + bc, &out[row*512 + colbase + nt*16 + ln]);
      }
    }
  }
}

extern "C" void kernel_launch(void* const* d_in, const int* in_sizes, int n_in,
                              void* d_out, int out_size, void* d_ws, size_t ws_size,
                              hipStream_t stream){
  const float* q  = (const float*)d_in[0];
  const float* k  = (const float*)d_in[1];
  const float* v  = (const float*)d_in[2];
  const float* Wq = (const float*)d_in[3];
  const float* bq = (const float*)d_in[4];
  const float* bk_ = (const float*)d_in[6];
  const float* Wk = (const float*)d_in[5];
  const float* Wv = (const float*)d_in[7];
  const float* bv = (const float*)d_in[8];
  const float* Wo = (const float*)d_in[9];
  const float* bo = (const float*)d_in[10];
  float* out = (float*)d_out;
  unsigned short* wsu = (unsigned short*)d_ws;

  k_prep<<<dim3(512), dim3(256), 0, stream>>>(Wq, Wk, Wv, Wo, wsu);
  k_proj<<<dim3(256, 3), dim3(128), 0, stream>>>(q, k, v, bq, bk_, bv, wsu);
  k_attn<<<dim3(64, 4), dim3(512), 0, stream>>>(wsu, bo, out);
}

// Round 5
// 45.085 us; speedup vs baseline: 1.0652x; 1.0652x over previous
//
#include <hip/hip_runtime.h>

typedef float f32x4 __attribute__((ext_vector_type(4)));
typedef short bf16x8 __attribute__((ext_vector_type(8)));
typedef __bf16 bf16x2_t __attribute__((ext_vector_type(2)));
typedef unsigned int u32;
typedef unsigned long long u64;

__device__ __forceinline__ u32 pk2(float a, float b){
  bf16x2_t h; h[0] = (__bf16)a; h[1] = (__bf16)b;
  return __builtin_bit_cast(u32, h);
}
__device__ __forceinline__ unsigned short f2bf(float f){
  __bf16 h = (__bf16)f;
  return __builtin_bit_cast(unsigned short, h);
}
__device__ __forceinline__ float bf2f(unsigned short h){
  u32 u = ((u32)h) << 16;
  return __builtin_bit_cast(float, u);
}

// ws layout in ushort (bf16) units
// Proj weights in MFMA-fragment order:
//   WF[which][ ((kc*4 + cg)*64 + lane)*8 + j ]  = W[k*64+n],
//   n = cg*16 + (lane&15), k = kc*32 + (lane>>4)*8 + j   (kc 0..15, cg 0..3)
#define WS_WF    0u        // 3 x 32768
#define WS_WOFT  98304u    // [512][64]  Wo_foldT[n][k] row-major
#define WS_QP    131072u   // [8192][64]  qp * 0.125*log2(e) folded
#define WS_KP    655360u   // [8192][64]
#define WS_VPT   1179648u  // [4][64][2048]  vp transposed per batch

#define QSCALE 0.18033688011112042f   // 0.125 * log2(e)

// ---------------- K1: fold Wo, build fragment-ordered bf16 weights ----------
__global__ __launch_bounds__(256) void k_prep(const float* __restrict__ Wq,
    const float* __restrict__ Wk, const float* __restrict__ Wv,
    const float* __restrict__ Wo, unsigned short* __restrict__ wsu){
  int id = blockIdx.x * 256 + threadIdx.x;   // grid 512*256 = 131072 exactly
  int which = id >> 15;
  int r = id & 32767;
  if (which < 3){
    const float* W = which==0 ? Wq : (which==1 ? Wk : Wv);
    int j   = r & 7;
    int l   = (r >> 3) & 63;
    int cg  = (r >> 9) & 3;
    int kc  = r >> 11;
    int n = cg*16 + (l & 15);
    int k = kc*32 + (l >> 4)*8 + j;
    wsu[which*32768u + r] = f2bf(W[k*64 + n]);
  } else {
    int n = r >> 6, k = r & 63;              // Wo_foldT[n][k] = sum_h Wo[h*64+k][n]
    float s = 0.f;
    #pragma unroll
    for (int h = 0; h < 8; ++h) s += Wo[(h*64 + k)*512 + n];
    wsu[WS_WOFT + r] = f2bf(s);
  }
}

// ---------------- K2: projection GEMM (8192x512)@(512x64) x3 ----------------
// 32 rows/block, 128 threads, grid (256,3); dbuf LDS, reg prefetch,
// B-operands loaded coalesced from fragment-ordered table.
__global__ __launch_bounds__(128) void k_proj(const float* __restrict__ q,
    const float* __restrict__ kmat, const float* __restrict__ v,
    const float* __restrict__ bq, const float* __restrict__ bk,
    const float* __restrict__ bv, unsigned short* __restrict__ wsu){
  __shared__ unsigned short Xs[2][2048];     // 2 x (32 rows x 64 k) bf16, XOR-swizzled
  const int which = blockIdx.y;
  const float* X    = which==0 ? q  : (which==1 ? kmat : v);
  const float* bias = which==0 ? bq : (which==1 ? bk   : bv);
  const unsigned short* WF = wsu + which*32768u;
  const int rowbase = blockIdx.x * 32;
  const int t = threadIdx.x;
  const int w = t >> 6, l = t & 63, g = l >> 4, ln = l & 15;

  f32x4 acc[2][2];                           // [rt][ntl]
  #pragma unroll
  for (int rt = 0; rt < 2; ++rt)
    #pragma unroll
    for (int ntl = 0; ntl < 2; ++ntl) acc[rt][ntl] = (f32x4){0.f,0.f,0.f,0.f};
  float bcol[2];
  #pragma unroll
  for (int ntl = 0; ntl < 2; ++ntl) bcol[ntl] = bias[(w*2+ntl)*16 + ln];

  f32x4 xr[4];
  bf16x8 bc[2][2], bn[2][2];

  // prologue: chunk 0 X + B (B: kc = i*2+kt, cg = w*2+ntl, lane-contiguous)
  #pragma unroll
  for (int j = 0; j < 4; ++j){
    int c = t + j*128; int row = c >> 4, kc = c & 15;
    xr[j] = __builtin_nontemporal_load(reinterpret_cast<const f32x4*>(X + (rowbase+row)*512 + kc*4));
  }
  #pragma unroll
  for (int ntl = 0; ntl < 2; ++ntl)
    #pragma unroll
    for (int kt = 0; kt < 2; ++kt)
      bc[ntl][kt] = *reinterpret_cast<const bf16x8*>(WF + (((0*2+kt)*4 + (w*2+ntl))*64 + l)*8);

  #pragma unroll
  for (int i = 0; i < 8; ++i){
    char* Xc = reinterpret_cast<char*>(Xs[i & 1]);
    // stage current chunk regs -> LDS (convert)
    #pragma unroll
    for (int j = 0; j < 4; ++j){
      int c = t + j*128; int row = c >> 4, kc = c & 15;
      u64 pk = (u64)pk2(xr[j][0], xr[j][1]) | ((u64)pk2(xr[j][2], xr[j][3]) << 32);
      *reinterpret_cast<u64*>(Xc + row*128 + ((kc*8) ^ ((row&7)<<4))) = pk;
    }
    // issue next chunk loads
    if (i < 7){
      #pragma unroll
      for (int j = 0; j < 4; ++j){
        int c = t + j*128; int row = c >> 4, kc = c & 15;
        xr[j] = __builtin_nontemporal_load(reinterpret_cast<const f32x4*>(X + (rowbase+row)*512 + (i+1)*64 + kc*4));
      }
    }
    __syncthreads();
    if (i < 7){
      #pragma unroll
      for (int ntl = 0; ntl < 2; ++ntl)
        #pragma unroll
        for (int kt = 0; kt < 2; ++kt)
          bn[ntl][kt] = *reinterpret_cast<const bf16x8*>(WF + ((((i+1)*2+kt)*4 + (w*2+ntl))*64 + l)*8);
    }
    bf16x8 a[2][2];
    #pragma unroll
    for (int rt = 0; rt < 2; ++rt){
      int arow = rt*16 + ln;
      #pragma unroll
      for (int kt = 0; kt < 2; ++kt)
        a[rt][kt] = *reinterpret_cast<const bf16x8*>(Xc + arow*128 + ((kt*64 + g*16) ^ ((arow&7)<<4)));
    }
    #pragma unroll
    for (int ntl = 0; ntl < 2; ++ntl)
      #pragma unroll
      for (int kt = 0; kt < 2; ++kt)
        #pragma unroll
        for (int rt = 0; rt < 2; ++rt)
          acc[rt][ntl] = __builtin_amdgcn_mfma_f32_16x16x32_bf16(a[rt][kt], bc[ntl][kt], acc[rt][ntl], 0, 0, 0);
    if (i < 7){
      #pragma unroll
      for (int ntl = 0; ntl < 2; ++ntl)
        #pragma unroll
        for (int kt = 0; kt < 2; ++kt)
          bc[ntl][kt] = bn[ntl][kt];
    }
  }

  if (which < 2){
    const float sc = (which==0) ? QSCALE : 1.0f;
    unsigned short* outp = wsu + (which==0 ? WS_QP : WS_KP);
    #pragma unroll
    for (int rt = 0; rt < 2; ++rt)
      #pragma unroll
      for (int ntl = 0; ntl < 2; ++ntl)
        #pragma unroll
        for (int r = 0; r < 4; ++r)
          outp[(rowbase + rt*16 + g*4 + r)*64 + (w*2+ntl)*16 + ln] = f2bf((acc[rt][ntl][r] + bcol[ntl]) * sc);
  } else {
    // V: round-trip through LDS, store transposed vpT[b][d][kv]
    __syncthreads();
    #pragma unroll
    for (int rt = 0; rt < 2; ++rt)
      #pragma unroll
      for (int ntl = 0; ntl < 2; ++ntl)
        #pragma unroll
        for (int r = 0; r < 4; ++r)
          Xs[0][(rt*16 + g*4 + r)*64 + (w*2+ntl)*16 + ln] = f2bf(acc[rt][ntl][r] + bcol[ntl]);
    __syncthreads();
    unsigned short* vpT = wsu + WS_VPT;
    const int b = rowbase >> 11;
    const int kvb = rowbase & 2047;
    const int d = t >> 1, seg = t & 1;       // 64 d x 2 segs of 16 kv
    bf16x8 v0, v1;
    #pragma unroll
    for (int i = 0; i < 8; ++i){
      v0[i] = (short)Xs[0][(seg*16 + i)*64 + d];
      v1[i] = (short)Xs[0][(seg*16 + 8 + i)*64 + d];
    }
    unsigned short* dst = vpT + ((unsigned)(b*64 + d))*2048u + kvb + seg*16;
    *reinterpret_cast<bf16x8*>(dst)     = v0;
    *reinterpret_cast<bf16x8*>(dst + 8) = v1;
  }
}

// ---------------- K3: split-KV flash attention + fused output projection ----
// KVBLK=64, 4 iters, ka prefetch; exp2-based softmax (scale folded into qp).
// LDS overlay: per-wave P buffer (stride 72 us) reused as partial-O (stride 68).
#define PSTR 72

__global__ __launch_bounds__(512, 2) void k_attn(const unsigned short* __restrict__ wsu,
    const float* __restrict__ bo, float* __restrict__ out){
  __shared__ __attribute__((aligned(16))) unsigned char smem[42496];
  // [0, 36864)      : per-wave region, w*4608: P rows 32 x stride 144B, then reused as po rows 32 x stride 136B
  // [36864, 37888)  : pls float[8][32]
  // [37888, 42496)  : ob ushort rows 32 x stride 144B

  const unsigned short* qp   = wsu + WS_QP;
  const unsigned short* kp   = wsu + WS_KP;
  const unsigned short* vpT  = wsu + WS_VPT;
  const unsigned short* WofT = wsu + WS_WOFT;

  const int t = threadIdx.x;
  const int w = t >> 6, l = t & 63, g = l >> 4, ln = l & 15;
  const int batch = blockIdx.y;
  const int qbase = batch*2048 + blockIdx.x*32;

  unsigned short* Pw  = (unsigned short*)(smem + w*4608);
  float*          pls = (float*)(smem + 36864);
  unsigned short* ob  = (unsigned short*)(smem + 37888);

  // Q fragments (B-operand: rows q = rt*16+ln, k = kt*32 + g*8 .. +7)
  bf16x8 qa[2][2];
  #pragma unroll
  for (int rt = 0; rt < 2; ++rt)
    #pragma unroll
    for (int kt = 0; kt < 2; ++kt)
      qa[rt][kt] = *reinterpret_cast<const bf16x8*>(qp + (qbase + rt*16 + ln)*64 + kt*32 + g*8);

  f32x4 o[4][2];                                 // O^T tiles [dt][rt]
  #pragma unroll
  for (int dt = 0; dt < 4; ++dt)
    #pragma unroll
    for (int rt = 0; rt < 2; ++rt) o[dt][rt] = (f32x4){0.f,0.f,0.f,0.f};
  float ls[2] = {0.f, 0.f};

  const unsigned short* kpb = kp  + batch*2048*64;
  const unsigned short* vpb = vpT + batch*64*2048;
  const int kv0 = w * 256;                       // this wave's KV slice

  bf16x8 ka[4][2];
  #pragma unroll
  for (int ct = 0; ct < 4; ++ct)
    #pragma unroll
    for (int kt = 0; kt < 2; ++kt)
      ka[ct][kt] = *reinterpret_cast<const bf16x8*>(kpb + (kv0 + ct*16 + ln)*64 + kt*32 + g*8);

  #pragma unroll
  for (int it = 0; it < 4; ++it){
    const int kvb = kv0 + it*64;
    // S^T(64kv x 32q) = mfma(A=K rows, B=Q rows); kv=ct*16+g*4+r, q=rt*16+ln
    f32x4 st[4][2];
    #pragma unroll
    for (int ct = 0; ct < 4; ++ct)
      #pragma unroll
      for (int rt = 0; rt < 2; ++rt){
        st[ct][rt] = (f32x4){0.f,0.f,0.f,0.f};
        #pragma unroll
        for (int kt = 0; kt < 2; ++kt)
          st[ct][rt] = __builtin_amdgcn_mfma_f32_16x16x32_bf16(ka[ct][kt], qa[rt][kt], st[ct][rt], 0,0,0);
      }
    // prefetch next iter's K fragments (hidden under softmax+PV)
    bf16x8 kan[4][2];
    if (it < 3){
      #pragma unroll
      for (int ct = 0; ct < 4; ++ct)
        #pragma unroll
        for (int kt = 0; kt < 2; ++kt)
          kan[ct][kt] = *reinterpret_cast<const bf16x8*>(kpb + (kvb + 64 + ct*16 + ln)*64 + kt*32 + g*8);
    }
    // V fragments for this iter (latency hidden under softmax)
    bf16x8 vb[4][2];
    #pragma unroll
    for (int dt = 0; dt < 4; ++dt)
      #pragma unroll
      for (int kvt = 0; kvt < 2; ++kvt)
        vb[dt][kvt] = *reinterpret_cast<const bf16x8*>(vpb + (dt*16 + ln)*2048 + kvb + kvt*32 + g*8);

    // softmax: p = exp2(st) (qp pre-scaled); lane-local sum + 2 shuffles
    #pragma unroll
    for (int rt = 0; rt < 2; ++rt){
      float p[4][4];
      float rs = 0.f;
      #pragma unroll
      for (int ct = 0; ct < 4; ++ct)
        #pragma unroll
        for (int r = 0; r < 4; ++r){
          p[ct][r] = exp2f(st[ct][rt][r]);
          rs += p[ct][r];
        }
      rs += __shfl_xor(rs, 16, 64);
      rs += __shfl_xor(rs, 32, 64);
      ls[rt] += rs;
      unsigned short* pr = Pw + (rt*16 + ln)*PSTR;
      #pragma unroll
      for (int ct = 0; ct < 4; ++ct){
        *reinterpret_cast<u32*>(pr + ct*16 + g*4)     = pk2(p[ct][0], p[ct][1]);
        *reinterpret_cast<u32*>(pr + ct*16 + g*4 + 2) = pk2(p[ct][2], p[ct][3]);
      }
    }
    // PV: O^T += mfma(A=V^T, B=P^T-as-B)  (wave-private LDS)
    bf16x8 pb[2][2];
    #pragma unroll
    for (int rt = 0; rt < 2; ++rt)
      #pragma unroll
      for (int kvt = 0; kvt < 2; ++kvt)
        pb[rt][kvt] = *reinterpret_cast<const bf16x8*>(Pw + (rt*16 + ln)*PSTR + kvt*32 + g*8);
    #pragma unroll
    for (int dt = 0; dt < 4; ++dt)
      #pragma unroll
      for (int rt = 0; rt < 2; ++rt)
        #pragma unroll
        for (int kvt = 0; kvt < 2; ++kvt)
          o[dt][rt] = __builtin_amdgcn_mfma_f32_16x16x32_bf16(vb[dt][kvt], pb[rt][kvt], o[dt][rt], 0,0,0);
    if (it < 3){
      #pragma unroll
      for (int ct = 0; ct < 4; ++ct)
        #pragma unroll
        for (int kt = 0; kt < 2; ++kt)
          ka[ct][kt] = kan[ct][kt];
    }
  }

  // write per-wave partials (overlay po on P region; data-dep ordering is safe)
  if (l < 16){ pls[w*32 + ln] = ls[0]; pls[w*32 + 16 + ln] = ls[1]; }
  unsigned short* pow_ = (unsigned short*)(smem + w*4608);
  #pragma unroll
  for (int dt = 0; dt < 4; ++dt)
    #pragma unroll
    for (int rt = 0; rt < 2; ++rt){
      u32* dst = reinterpret_cast<u32*>(pow_ + (rt*16 + ln)*68 + dt*16 + g*4);
      dst[0] = pk2(o[dt][rt][0], o[dt][rt][1]);
      dst[1] = pk2(o[dt][rt][2], o[dt][rt][3]);
    }
  __syncthreads();

  // merge 8 wave-partials -> normalized O (bf16, stride 72)
  #pragma unroll
  for (int i = 0; i < 4; ++i){
    int idx = t + i*512;
    int row = idx >> 6, d = idx & 63;
    float den = 0.f, num = 0.f;
    #pragma unroll
    for (int w2 = 0; w2 < 8; ++w2){
      den += pls[w2*32 + row];
      num += bf2f(*((const unsigned short*)(smem + w2*4608) + row*68 + d));
    }
    ob[row*PSTR + d] = f2bf(num / den);
  }
  __syncthreads();

  // output projection: out(32x512) = O(32x64) @ Wo_fold(64x512), + bo
  const int colbase = w*64;
  bf16x8 ao[2][2];
  #pragma unroll
  for (int rt = 0; rt < 2; ++rt)
    #pragma unroll
    for (int kt = 0; kt < 2; ++kt)
      ao[rt][kt] = *reinterpret_cast<const bf16x8*>(ob + (rt*16 + ln)*PSTR + kt*32 + g*8);
  f32x4 oc[2][4];
  #pragma unroll
  for (int rt = 0; rt < 2; ++rt)
    #pragma unroll
    for (int nt = 0; nt < 4; ++nt) oc[rt][nt] = (f32x4){0.f,0.f,0.f,0.f};
  #pragma unroll
  for (int nt = 0; nt < 4; ++nt){
    #pragma unroll
    for (int kt = 0; kt < 2; ++kt){
      bf16x8 b = *reinterpret_cast<const bf16x8*>(WofT + (colbase + nt*16 + ln)*64 + kt*32 + g*8);
      #pragma unroll
      for (int rt = 0; rt < 2; ++rt)
        oc[rt][nt] = __builtin_amdgcn_mfma_f32_16x16x32_bf16(ao[rt][kt], b, oc[rt][nt], 0,0,0);
    }
  }
  #pragma unroll
  for (int nt = 0; nt < 4; ++nt){
    float bc = bo[colbase + nt*16 + ln];
    #pragma unroll
    for (int rt = 0; rt < 2; ++rt){
      #pragma unroll
      for (int r = 0; r < 4; ++r){
        int row = qbase + rt*16 + g*4 + r;
        __builtin_nontemporal_store(oc[rt][nt][r] + bc, &out[row*512 + colbase + nt*16 + ln]);
      }
    }
  }
}

extern "C" void kernel_launch(void* const* d_in, const int* in_sizes, int n_in,
                              void* d_out, int out_size, void* d_ws, size_t ws_size,
                              hipStream_t stream){
  const float* q  = (const float*)d_in[0];
  const float* k  = (const float*)d_in[1];
  const float* v  = (const float*)d_in[2];
  const float* Wq = (const float*)d_in[3];
  const float* bq = (const float*)d_in[4];
  const float* Wk = (const float*)d_in[5];
  const float* bk = (const float*)d_in[6];
  const float* Wv = (const float*)d_in[7];
  const float* bv = (const float*)d_in[8];
  const float* Wo = (const float*)d_in[9];
  const float* bo = (const float*)d_in[10];
  float* out = (float*)d_out;
  unsigned short* wsu = (unsigned short*)d_ws;

  k_prep<<<dim3(512), dim3(256), 0, stream>>>(Wq, Wk, Wv, Wo, wsu);
  k_proj<<<dim3(256, 3), dim3(128), 0, stream>>>(q, k, v, bq, bk, bv, wsu);
  k_attn<<<dim3(64, 4), dim3(512), 0, stream>>>(wsu, bo, out);
}

// Round 6
// 44.100 us; speedup vs baseline: 1.0890x; 1.0223x over previous
//
#include <hip/hip_runtime.h>

typedef float f32x4 __attribute__((ext_vector_type(4)));
typedef short bf16x8 __attribute__((ext_vector_type(8)));
typedef __bf16 bf16x2_t __attribute__((ext_vector_type(2)));
typedef unsigned int u32;
typedef unsigned long long u64;

__device__ __forceinline__ u32 pk2(float a, float b){
  bf16x2_t h; h[0] = (__bf16)a; h[1] = (__bf16)b;
  return __builtin_bit_cast(u32, h);
}
__device__ __forceinline__ unsigned short f2bf(float f){
  __bf16 h = (__bf16)f;
  return __builtin_bit_cast(unsigned short, h);
}
__device__ __forceinline__ float bf2f(unsigned short h){
  u32 u = ((u32)h) << 16;
  return __builtin_bit_cast(float, u);
}

// ws layout in ushort (bf16) units
// Proj weights in MFMA-fragment order:
//   WF[which][ ((kc*4 + cg)*64 + lane)*8 + j ]  = W[k*64+n],
//   n = cg*16 + (lane&15), k = kc*32 + (lane>>4)*8 + j   (kc 0..15, cg 0..3)
#define WS_WF    0u        // 3 x 32768
#define WS_WOFT  98304u    // [512][64]  Wo_foldT[n][k] row-major
#define WS_QP    131072u   // [8192][64]  qp * 0.125*log2(e) folded
#define WS_KP    655360u   // [8192][64]
#define WS_VPT   1179648u  // [4][64][2048]  vp transposed per batch

#define QSCALE 0.18033688011112042f   // 0.125 * log2(e)

// ---------------- K1: fold Wo, build fragment-ordered bf16 weights ----------
__global__ __launch_bounds__(256) void k_prep(const float* __restrict__ Wq,
    const float* __restrict__ Wk, const float* __restrict__ Wv,
    const float* __restrict__ Wo, unsigned short* __restrict__ wsu){
  int id = blockIdx.x * 256 + threadIdx.x;   // grid 512*256 = 131072 exactly
  int which = id >> 15;
  int r = id & 32767;
  if (which < 3){
    const float* W = which==0 ? Wq : (which==1 ? Wk : Wv);
    int j   = r & 7;
    int l   = (r >> 3) & 63;
    int cg  = (r >> 9) & 3;
    int kc  = r >> 11;
    int n = cg*16 + (l & 15);
    int k = kc*32 + (l >> 4)*8 + j;
    wsu[which*32768u + r] = f2bf(W[k*64 + n]);
  } else {
    int n = r >> 6, k = r & 63;              // Wo_foldT[n][k] = sum_h Wo[h*64+k][n]
    float s = 0.f;
    #pragma unroll
    for (int h = 0; h < 8; ++h) s += Wo[(h*64 + k)*512 + n];
    wsu[WS_WOFT + r] = f2bf(s);
  }
}

// ---------------- K2: projection GEMM (8192x512)@(512x64) x3 ----------------
// 32 rows/block, 128 threads, grid (256,3); dbuf LDS, reg prefetch,
// B-operands loaded coalesced from fragment-ordered table.
__global__ __launch_bounds__(128) void k_proj(const float* __restrict__ q,
    const float* __restrict__ kmat, const float* __restrict__ v,
    const float* __restrict__ bq, const float* __restrict__ bk,
    const float* __restrict__ bv, unsigned short* __restrict__ wsu){
  __shared__ unsigned short Xs[2][2048];     // 2 x (32 rows x 64 k) bf16, XOR-swizzled
  const int which = blockIdx.y;
  const float* X    = which==0 ? q  : (which==1 ? kmat : v);
  const float* bias = which==0 ? bq : (which==1 ? bk   : bv);
  const unsigned short* WF = wsu + which*32768u;
  const int rowbase = blockIdx.x * 32;
  const int t = threadIdx.x;
  const int w = t >> 6, l = t & 63, g = l >> 4, ln = l & 15;

  f32x4 acc[2][2];                           // [rt][ntl]
  #pragma unroll
  for (int rt = 0; rt < 2; ++rt)
    #pragma unroll
    for (int ntl = 0; ntl < 2; ++ntl) acc[rt][ntl] = (f32x4){0.f,0.f,0.f,0.f};
  float bcol[2];
  #pragma unroll
  for (int ntl = 0; ntl < 2; ++ntl) bcol[ntl] = bias[(w*2+ntl)*16 + ln];

  f32x4 xr[4];
  bf16x8 bc[2][2], bn[2][2];

  // prologue: chunk 0 X + B (B: kc = i*2+kt, cg = w*2+ntl, lane-contiguous)
  #pragma unroll
  for (int j = 0; j < 4; ++j){
    int c = t + j*128; int row = c >> 4, kc = c & 15;
    xr[j] = __builtin_nontemporal_load(reinterpret_cast<const f32x4*>(X + (rowbase+row)*512 + kc*4));
  }
  #pragma unroll
  for (int ntl = 0; ntl < 2; ++ntl)
    #pragma unroll
    for (int kt = 0; kt < 2; ++kt)
      bc[ntl][kt] = *reinterpret_cast<const bf16x8*>(WF + (((0*2+kt)*4 + (w*2+ntl))*64 + l)*8);

  #pragma unroll
  for (int i = 0; i < 8; ++i){
    char* Xc = reinterpret_cast<char*>(Xs[i & 1]);
    // stage current chunk regs -> LDS (convert)
    #pragma unroll
    for (int j = 0; j < 4; ++j){
      int c = t + j*128; int row = c >> 4, kc = c & 15;
      u64 pk = (u64)pk2(xr[j][0], xr[j][1]) | ((u64)pk2(xr[j][2], xr[j][3]) << 32);
      *reinterpret_cast<u64*>(Xc + row*128 + ((kc*8) ^ ((row&7)<<4))) = pk;
    }
    // issue next chunk loads
    if (i < 7){
      #pragma unroll
      for (int j = 0; j < 4; ++j){
        int c = t + j*128; int row = c >> 4, kc = c & 15;
        xr[j] = __builtin_nontemporal_load(reinterpret_cast<const f32x4*>(X + (rowbase+row)*512 + (i+1)*64 + kc*4));
      }
    }
    __syncthreads();
    if (i < 7){
      #pragma unroll
      for (int ntl = 0; ntl < 2; ++ntl)
        #pragma unroll
        for (int kt = 0; kt < 2; ++kt)
          bn[ntl][kt] = *reinterpret_cast<const bf16x8*>(WF + ((((i+1)*2+kt)*4 + (w*2+ntl))*64 + l)*8);
    }
    bf16x8 a[2][2];
    #pragma unroll
    for (int rt = 0; rt < 2; ++rt){
      int arow = rt*16 + ln;
      #pragma unroll
      for (int kt = 0; kt < 2; ++kt)
        a[rt][kt] = *reinterpret_cast<const bf16x8*>(Xc + arow*128 + ((kt*64 + g*16) ^ ((arow&7)<<4)));
    }
    #pragma unroll
    for (int ntl = 0; ntl < 2; ++ntl)
      #pragma unroll
      for (int kt = 0; kt < 2; ++kt)
        #pragma unroll
        for (int rt = 0; rt < 2; ++rt)
          acc[rt][ntl] = __builtin_amdgcn_mfma_f32_16x16x32_bf16(a[rt][kt], bc[ntl][kt], acc[rt][ntl], 0, 0, 0);
    if (i < 7){
      #pragma unroll
      for (int ntl = 0; ntl < 2; ++ntl)
        #pragma unroll
        for (int kt = 0; kt < 2; ++kt)
          bc[ntl][kt] = bn[ntl][kt];
    }
  }

  if (which < 2){
    const float sc = (which==0) ? QSCALE : 1.0f;
    unsigned short* outp = wsu + (which==0 ? WS_QP : WS_KP);
    #pragma unroll
    for (int rt = 0; rt < 2; ++rt)
      #pragma unroll
      for (int ntl = 0; ntl < 2; ++ntl)
        #pragma unroll
        for (int r = 0; r < 4; ++r)
          outp[(rowbase + rt*16 + g*4 + r)*64 + (w*2+ntl)*16 + ln] = f2bf((acc[rt][ntl][r] + bcol[ntl]) * sc);
  } else {
    // V: round-trip through LDS, store transposed vpT[b][d][kv]
    __syncthreads();
    #pragma unroll
    for (int rt = 0; rt < 2; ++rt)
      #pragma unroll
      for (int ntl = 0; ntl < 2; ++ntl)
        #pragma unroll
        for (int r = 0; r < 4; ++r)
          Xs[0][(rt*16 + g*4 + r)*64 + (w*2+ntl)*16 + ln] = f2bf(acc[rt][ntl][r] + bcol[ntl]);
    __syncthreads();
    unsigned short* vpT = wsu + WS_VPT;
    const int b = rowbase >> 11;
    const int kvb = rowbase & 2047;
    const int d = t >> 1, seg = t & 1;       // 64 d x 2 segs of 16 kv
    bf16x8 v0, v1;
    #pragma unroll
    for (int i = 0; i < 8; ++i){
      v0[i] = (short)Xs[0][(seg*16 + i)*64 + d];
      v1[i] = (short)Xs[0][(seg*16 + 8 + i)*64 + d];
    }
    unsigned short* dst = vpT + ((unsigned)(b*64 + d))*2048u + kvb + seg*16;
    *reinterpret_cast<bf16x8*>(dst)     = v0;
    *reinterpret_cast<bf16x8*>(dst + 8) = v1;
  }
}

// ---------------- K3: split-KV flash attention + fused output projection ----
// KVBLK=64, 4 iters; exp2-based softmax (scale folded into qp).
// No forced occupancy cap, no K prefetch: keep VGPR <= 256 so nothing spills.
#define PSTR 72

__global__ __launch_bounds__(512) void k_attn(const unsigned short* __restrict__ wsu,
    const float* __restrict__ bo, float* __restrict__ out){
  __shared__ __attribute__((aligned(16))) unsigned char smem[42496];
  // [0, 36864)      : per-wave region, w*4608: P rows 32 x stride 144B, then reused as po rows 32 x stride 136B
  // [36864, 37888)  : pls float[8][32]
  // [37888, 42496)  : ob ushort rows 32 x stride 144B

  const unsigned short* qp   = wsu + WS_QP;
  const unsigned short* kp   = wsu + WS_KP;
  const unsigned short* vpT  = wsu + WS_VPT;
  const unsigned short* WofT = wsu + WS_WOFT;

  const int t = threadIdx.x;
  const int w = t >> 6, l = t & 63, g = l >> 4, ln = l & 15;
  const int batch = blockIdx.y;
  const int qbase = batch*2048 + blockIdx.x*32;

  unsigned short* Pw  = (unsigned short*)(smem + w*4608);
  float*          pls = (float*)(smem + 36864);
  unsigned short* ob  = (unsigned short*)(smem + 37888);

  // Q fragments (B-operand: rows q = rt*16+ln, k = kt*32 + g*8 .. +7)
  bf16x8 qa[2][2];
  #pragma unroll
  for (int rt = 0; rt < 2; ++rt)
    #pragma unroll
    for (int kt = 0; kt < 2; ++kt)
      qa[rt][kt] = *reinterpret_cast<const bf16x8*>(qp + (qbase + rt*16 + ln)*64 + kt*32 + g*8);

  f32x4 o[4][2];                                 // O^T tiles [dt][rt]
  #pragma unroll
  for (int dt = 0; dt < 4; ++dt)
    #pragma unroll
    for (int rt = 0; rt < 2; ++rt) o[dt][rt] = (f32x4){0.f,0.f,0.f,0.f};
  float ls[2] = {0.f, 0.f};

  const unsigned short* kpb = kp  + batch*2048*64;
  const unsigned short* vpb = vpT + batch*64*2048;
  const int kv0 = w * 256;                       // this wave's KV slice

  #pragma unroll
  for (int it = 0; it < 4; ++it){
    const int kvb = kv0 + it*64;
    // K fragments for this iter (L2-resident; short live range)
    bf16x8 ka[4][2];
    #pragma unroll
    for (int ct = 0; ct < 4; ++ct)
      #pragma unroll
      for (int kt = 0; kt < 2; ++kt)
        ka[ct][kt] = *reinterpret_cast<const bf16x8*>(kpb + (kvb + ct*16 + ln)*64 + kt*32 + g*8);
    // S^T(64kv x 32q) = mfma(A=K rows, B=Q rows); kv=ct*16+g*4+r, q=rt*16+ln
    f32x4 st[4][2];
    #pragma unroll
    for (int ct = 0; ct < 4; ++ct)
      #pragma unroll
      for (int rt = 0; rt < 2; ++rt){
        st[ct][rt] = (f32x4){0.f,0.f,0.f,0.f};
        #pragma unroll
        for (int kt = 0; kt < 2; ++kt)
          st[ct][rt] = __builtin_amdgcn_mfma_f32_16x16x32_bf16(ka[ct][kt], qa[rt][kt], st[ct][rt], 0,0,0);
      }
    // V fragments for this iter (latency hidden under softmax)
    bf16x8 vb[4][2];
    #pragma unroll
    for (int dt = 0; dt < 4; ++dt)
      #pragma unroll
      for (int kvt = 0; kvt < 2; ++kvt)
        vb[dt][kvt] = *reinterpret_cast<const bf16x8*>(vpb + (dt*16 + ln)*2048 + kvb + kvt*32 + g*8);

    // softmax: p = exp2(st) (qp pre-scaled); lane-local sum + 2 shuffles
    #pragma unroll
    for (int rt = 0; rt < 2; ++rt){
      float p[4][4];
      float rs = 0.f;
      #pragma unroll
      for (int ct = 0; ct < 4; ++ct)
        #pragma unroll
        for (int r = 0; r < 4; ++r){
          p[ct][r] = exp2f(st[ct][rt][r]);
          rs += p[ct][r];
        }
      rs += __shfl_xor(rs, 16, 64);
      rs += __shfl_xor(rs, 32, 64);
      ls[rt] += rs;
      unsigned short* pr = Pw + (rt*16 + ln)*PSTR;
      #pragma unroll
      for (int ct = 0; ct < 4; ++ct){
        *reinterpret_cast<u32*>(pr + ct*16 + g*4)     = pk2(p[ct][0], p[ct][1]);
        *reinterpret_cast<u32*>(pr + ct*16 + g*4 + 2) = pk2(p[ct][2], p[ct][3]);
      }
    }
    // PV: O^T += mfma(A=V^T, B=P^T-as-B)  (wave-private LDS)
    bf16x8 pb[2][2];
    #pragma unroll
    for (int rt = 0; rt < 2; ++rt)
      #pragma unroll
      for (int kvt = 0; kvt < 2; ++kvt)
        pb[rt][kvt] = *reinterpret_cast<const bf16x8*>(Pw + (rt*16 + ln)*PSTR + kvt*32 + g*8);
    #pragma unroll
    for (int dt = 0; dt < 4; ++dt)
      #pragma unroll
      for (int rt = 0; rt < 2; ++rt)
        #pragma unroll
        for (int kvt = 0; kvt < 2; ++kvt)
          o[dt][rt] = __builtin_amdgcn_mfma_f32_16x16x32_bf16(vb[dt][kvt], pb[rt][kvt], o[dt][rt], 0,0,0);
  }

  // write per-wave partials (overlay po on P region; data-dep ordering is safe)
  if (l < 16){ pls[w*32 + ln] = ls[0]; pls[w*32 + 16 + ln] = ls[1]; }
  unsigned short* pow_ = (unsigned short*)(smem + w*4608);
  #pragma unroll
  for (int dt = 0; dt < 4; ++dt)
    #pragma unroll
    for (int rt = 0; rt < 2; ++rt){
      u32* dst = reinterpret_cast<u32*>(pow_ + (rt*16 + ln)*68 + dt*16 + g*4);
      dst[0] = pk2(o[dt][rt][0], o[dt][rt][1]);
      dst[1] = pk2(o[dt][rt][2], o[dt][rt][3]);
    }
  __syncthreads();

  // merge 8 wave-partials -> normalized O (bf16, stride 72)
  #pragma unroll
  for (int i = 0; i < 4; ++i){
    int idx = t + i*512;
    int row = idx >> 6, d = idx & 63;
    float den = 0.f, num = 0.f;
    #pragma unroll
    for (int w2 = 0; w2 < 8; ++w2){
      den += pls[w2*32 + row];
      num += bf2f(*((const unsigned short*)(smem + w2*4608) + row*68 + d));
    }
    ob[row*PSTR + d] = f2bf(num / den);
  }
  __syncthreads();

  // output projection: out(32x512) = O(32x64) @ Wo_fold(64x512), + bo
  const int colbase = w*64;
  bf16x8 ao[2][2];
  #pragma unroll
  for (int rt = 0; rt < 2; ++rt)
    #pragma unroll
    for (int kt = 0; kt < 2; ++kt)
      ao[rt][kt] = *reinterpret_cast<const bf16x8*>(ob + (rt*16 + ln)*PSTR + kt*32 + g*8);
  f32x4 oc[2][4];
  #pragma unroll
  for (int rt = 0; rt < 2; ++rt)
    #pragma unroll
    for (int nt = 0; nt < 4; ++nt) oc[rt][nt] = (f32x4){0.f,0.f,0.f,0.f};
  #pragma unroll
  for (int nt = 0; nt < 4; ++nt){
    #pragma unroll
    for (int kt = 0; kt < 2; ++kt){
      bf16x8 b = *reinterpret_cast<const bf16x8*>(WofT + (colbase + nt*16 + ln)*64 + kt*32 + g*8);
      #pragma unroll
      for (int rt = 0; rt < 2; ++rt)
        oc[rt][nt] = __builtin_amdgcn_mfma_f32_16x16x32_bf16(ao[rt][kt], b, oc[rt][nt], 0,0,0);
    }
  }
  #pragma unroll
  for (int nt = 0; nt < 4; ++nt){
    float bc = bo[colbase + nt*16 + ln];
    #pragma unroll
    for (int rt = 0; rt < 2; ++rt){
      #pragma unroll
      for (int r = 0; r < 4; ++r){
        int row = qbase + rt*16 + g*4 + r;
        __builtin_nontemporal_store(oc[rt][nt][r] + bc, &out[row*512 + colbase + nt*16 + ln]);
      }
    }
  }
}

extern "C" void kernel_launch(void* const* d_in, const int* in_sizes, int n_in,
                              void* d_out, int out_size, void* d_ws, size_t ws_size,
                              hipStream_t stream){
  const float* q  = (const float*)d_in[0];
  const float* k  = (const float*)d_in[1];
  const float* v  = (const float*)d_in[2];
  const float* Wq = (const float*)d_in[3];
  const float* bq = (const float*)d_in[4];
  const float* Wk = (const float*)d_in[5];
  const float* bk = (const float*)d_in[6];
  const float* Wv = (const float*)d_in[7];
  const float* bv = (const float*)d_in[8];
  const float* Wo = (const float*)d_in[9];
  const float* bo = (const float*)d_in[10];
  float* out = (float*)d_out;
  unsigned short* wsu = (unsigned short*)d_ws;

  k_prep<<<dim3(512), dim3(256), 0, stream>>>(Wq, Wk, Wv, Wo, wsu);
  k_proj<<<dim3(256, 3), dim3(128), 0, stream>>>(q, k, v, bq, bk, bv, wsu);
  k_attn<<<dim3(64, 4), dim3(512), 0, stream>>>(wsu, bo, out);
}